// Round 8
// baseline (2865.533 us; speedup 1.0000x reference)
//
#include <hip/hip_runtime.h>

// ResidualVectorQuantizer: N=131072, DIM=128, LEVELS=3, K=1024, BETA=0.25, USAGE_REG=1e-3
// Outputs (flat fp32 in d_out): quantized [N*128] | codes [N*3] | commit | usage
//
// Numerics contract with the np fp32 reference (validated previously — do not change):
//  - m = x·W_k: strict sequential fmaf chain over k=0..127, single accumulator.
//  - d = (S - 2*m) + w via __fsub_rn/__fmul_rn/__fadd_rn (no contraction).
//  - argmin: first occurrence on ties == lexicographic (value, index) min.
//    (round 13: implemented as value-min butterfly + exact-equality first-index
//     + index-min butterfly — bit-identical result, ~35% fewer ops)
//  - residual chain (x - q0) - q1 elementwise fp32, recomputed from codes per level.
//  - Srow: per-8-elem left-assoc square sums, then 16-chunk ascending sum.
//  - losses: tolerance loose (~2%); commit = sum of d at argmin; avgp fp32;
//    KL f64. Phase-3 exp switched to __expf (probs-only path; codes/commit
//    unaffected; usage delta ~1e-6 << tolerance).
//
// Round 13. r7 (LDS-tiled GEMM, 512t, 16x2/thread) = 910 us/level, total 2402:
// FIRST structural win, and the allocator behaved (VGPR=44, no spill) because
// the occupancy target was LDS-limited — the escape from the 6-round register
// war. Remaining fat: FMA only 24% of cycles (4096 FMA vs ~2000 overhead ops
// per thread), 8.27M bank conflicts (float2 Wt read = stride-8B = 4-way), and
// libm expf ~20 inst. This round: 256 threads, 16 rows x 4 codes/thread
// (acc 64 = the r0-r5 validated chain shape), KT=2, Wtile[2][2048]:
//  - per k: 1 conflict-free b128 wv + 4 broadcast rv per 64 FMA (2x density)
//  - LDS ~28.5 KB -> 5 blocks/CU -> LDS-limited reg budget 102 >= ~98 live
//  - cheap argmin (value butterfly + equality first-idx), __expf
// Checks: VGPR 90-102 (if 64 + WRITE spike -> allocator lost, halve acc next),
// bank conflicts < 1M, WRITE ~67-134MB, dur 500-650/level.

#define NROWS   131072
#define DIMS    128
#define KCODES  1024
#define NLEV    3

#define QF_OFF   ((size_t)NROWS * DIMS)          // 16777216
#define CODE_OFF QF_OFF
#define SCAL_OFF (QF_OFF + (size_t)NROWS * 3)    // 17170432

// ---------------- ws layout ----------------
// avgp   : 3*1024 floats  @ 0        (12288 B)
// commit : 3 doubles      @ 12288    (24 B)
// wk     : 3*1024 floats  @ 12320    (12288 B)
// WT     : 3*128*1024 fl  @ 24608    (1572864 B)  k-major codebooks WT[l][k][c]
#define WS_COMMIT_OFF 12288
#define WS_WK_OFF     12320
#define WS_WT_OFF     24608

__global__ __launch_bounds__(256) void init_acc(float* avgp, double* commit) {
    for (int i = threadIdx.x; i < 3072; i += 256) avgp[i] = 0.0f;
    if (threadIdx.x < 3) commit[threadIdx.x] = 0.0;
}

__global__ __launch_bounds__(256) void wnorm_kernel(const float* __restrict__ W,
                                                    float* __restrict__ wk) {
    const int wave = threadIdx.x >> 6, lane = threadIdx.x & 63;
    const int c = blockIdx.x * 4 + wave;          // 0..3071 (level*1024 + k)
    const float2 v = *(const float2*)(W + (size_t)c * DIMS + 2 * lane);
    float s = v.x * v.x + v.y * v.y;
#pragma unroll
    for (int m = 32; m >= 1; m >>= 1) s += __shfl_xor(s, m, 64);
    if (lane == 0) wk[c] = s;
}

// WT[l][k][c] = W[l][c][k]   (plain k-major)
__global__ __launch_bounds__(256) void transpose_w(const float* __restrict__ W,
                                                   float* __restrict__ WT) {
    __shared__ float tile[32][65];
    const int l = blockIdx.z, k0 = blockIdx.y * 32, c0 = blockIdx.x * 64;
    const float* Wl = W + (size_t)l * KCODES * DIMS;
    float* WTl = WT + (size_t)l * DIMS * KCODES;
    {
        const int ci = threadIdx.x >> 2;            // 0..63
        const int kg = (threadIdx.x & 3) * 8;       // 0,8,16,24
        const float4 a = *(const float4*)(Wl + (size_t)(c0 + ci) * DIMS + k0 + kg);
        const float4 b = *(const float4*)(Wl + (size_t)(c0 + ci) * DIMS + k0 + kg + 4);
        tile[kg + 0][ci] = a.x; tile[kg + 1][ci] = a.y;
        tile[kg + 2][ci] = a.z; tile[kg + 3][ci] = a.w;
        tile[kg + 4][ci] = b.x; tile[kg + 5][ci] = b.y;
        tile[kg + 6][ci] = b.z; tile[kg + 7][ci] = b.w;
    }
    __syncthreads();
    {
        const int k = threadIdx.x >> 3;             // 0..31
        const int cg = (threadIdx.x & 7) * 8;       // 0..56
        float4 o0, o1;
        o0.x = tile[k][cg + 0]; o0.y = tile[k][cg + 1];
        o0.z = tile[k][cg + 2]; o0.w = tile[k][cg + 3];
        o1.x = tile[k][cg + 4]; o1.y = tile[k][cg + 5];
        o1.z = tile[k][cg + 6]; o1.w = tile[k][cg + 7];
        *(float4*)(WTl + (size_t)(k0 + k) * KCODES + c0 + cg)     = o0;
        *(float4*)(WTl + (size_t)(k0 + k) * KCODES + c0 + cg + 4) = o1;
    }
}

// In-place FMA on the accumulator (same fmaf chain order as all prior rounds).
#define FMA4(A, rs, wv)                                                        \
    A.x = fmaf(rs, wv.x, A.x); A.y = fmaf(rs, wv.y, A.y);                      \
    A.z = fmaf(rs, wv.z, A.z); A.w = fmaf(rs, wv.w, A.w);

__global__ __launch_bounds__(256) void rvq_level(
    const float* __restrict__ x, const float* __restrict__ W,
    const float* __restrict__ WT, const float* __restrict__ wk,
    float* __restrict__ out, float* __restrict__ avgp,
    double* __restrict__ commit, const int level) {

    __shared__ float Wtile[2][2048];   // double-buffered W tile: 2 k-rows x 1024
    __shared__ float rowT[128][20];    // residual rows, k-major (80B row stride: 16B-aligned)
    __shared__ float redf[16][17];
    __shared__ float Srow[16];
    __shared__ float wminv[16][4];     // per-wave argmin partials (4 waves)
    __shared__ int   wmini[16][4];
    __shared__ float rowmin[16];
    __shared__ float wsum[16][4];
    __shared__ float rcpL[16];

    const int t = threadIdx.x;
    const int wave = t >> 6, lane = t & 63;
    const int c = wave * 256 + lane * 4;          // this thread's 4 codes
    const size_t base = (size_t)blockIdx.x * 16;
    const float* codesF = out + CODE_OFF;
    const float* WTl = WT + (size_t)level * DIMS * KCODES;
    const float* wkl = wk + level * KCODES;

    // ---- phase 0: stage 16 residual rows (k-major), bit-exact chain ----
    {
        const int r = t >> 4, i = t & 15;
        const size_t n = base + r;
        float4 v0 = *(const float4*)(x + n * DIMS + i * 8);
        float4 v1 = *(const float4*)(x + n * DIMS + i * 8 + 4);
        for (int j = 0; j < level; ++j) {
            const int idx = (int)codesF[n * 3 + j];
            const float* q = W + ((size_t)(j * KCODES + idx)) * DIMS + i * 8;
            const float4 q0 = *(const float4*)q;
            const float4 q1 = *(const float4*)(q + 4);
            v0.x = __fsub_rn(v0.x, q0.x); v0.y = __fsub_rn(v0.y, q0.y);
            v0.z = __fsub_rn(v0.z, q0.z); v0.w = __fsub_rn(v0.w, q0.w);
            v1.x = __fsub_rn(v1.x, q1.x); v1.y = __fsub_rn(v1.y, q1.y);
            v1.z = __fsub_rn(v1.z, q1.z); v1.w = __fsub_rn(v1.w, q1.w);
        }
        rowT[i * 8 + 0][r] = v0.x; rowT[i * 8 + 1][r] = v0.y;
        rowT[i * 8 + 2][r] = v0.z; rowT[i * 8 + 3][r] = v0.w;
        rowT[i * 8 + 4][r] = v1.x; rowT[i * 8 + 5][r] = v1.y;
        rowT[i * 8 + 6][r] = v1.z; rowT[i * 8 + 7][r] = v1.w;
        float sq = v0.x * v0.x + v0.y * v0.y + v0.z * v0.z + v0.w * v0.w
                 + v1.x * v1.x + v1.y * v1.y + v1.z * v1.z + v1.w * v1.w;
        redf[r][i] = sq;
    }
    __syncthreads();
    if (t < 16) {
        float s = 0.f;
        for (int i = 0; i < 16; ++i) s += redf[t][i];
        Srow[t] = s;   // on-grid shift: order can't affect argmin/softmax
    }

    // ---- phase 1: tiled GEMM. acc[r] = row_r · W_{c..c+3}, k ascending. ----
    float4 acc[16];
#pragma unroll
    for (int r = 0; r < 16; ++r) { acc[r].x = 0.f; acc[r].y = 0.f; acc[r].z = 0.f; acc[r].w = 0.f; }

    // prologue: stage tile 0 (k-rows 0,1) into buf 0 via registers
    {
        const float4 g0 = *(const float4*)(WTl + t * 4);
        const float4 g1 = *(const float4*)(WTl + 1024 + t * 4);
        *(float4*)&Wtile[0][t * 4]        = g0;
        *(float4*)&Wtile[0][1024 + t * 4] = g1;
    }
    __syncthreads();   // covers Srow + tile 0

    int buf = 0;
#pragma unroll 1
    for (int kt = 0; kt < 64; ++kt) {
        // issue-early: global loads for tile kt+1 (clamped; dead on last iter)
        const float* Wn = WTl + (size_t)((kt + 1 < 64) ? (kt + 1) : 0) * 2048;
        const float4 g0 = *(const float4*)(Wn + t * 4);
        const float4 g1 = *(const float4*)(Wn + 1024 + t * 4);

        // consume current tile: 2 k-steps x 16 rows x 4 codes
        const float* Wt = &Wtile[buf][0];
        {   // k = 2*kt
            const float4 wv = *(const float4*)&Wt[c];          // 64 lanes x 16B contiguous
#pragma unroll
            for (int rr = 0; rr < 4; ++rr) {
                const float4 rv = *(const float4*)&rowT[2 * kt][rr * 4];   // broadcast
                FMA4(acc[rr * 4 + 0], rv.x, wv);
                FMA4(acc[rr * 4 + 1], rv.y, wv);
                FMA4(acc[rr * 4 + 2], rv.z, wv);
                FMA4(acc[rr * 4 + 3], rv.w, wv);
            }
        }
        {   // k = 2*kt+1
            const float4 wv = *(const float4*)&Wt[1024 + c];
#pragma unroll
            for (int rr = 0; rr < 4; ++rr) {
                const float4 rv = *(const float4*)&rowT[2 * kt + 1][rr * 4];
                FMA4(acc[rr * 4 + 0], rv.x, wv);
                FMA4(acc[rr * 4 + 1], rv.y, wv);
                FMA4(acc[rr * 4 + 2], rv.z, wv);
                FMA4(acc[rr * 4 + 3], rv.w, wv);
            }
        }

        // write-late: vmcnt wait lands here, AFTER the ~512-cycle FMA block (T14)
        *(float4*)&Wtile[buf ^ 1][t * 4]        = g0;
        *(float4*)&Wtile[buf ^ 1][1024 + t * 4] = g1;
        __syncthreads();
        buf ^= 1;
    }

    // ---- phase 2: d in place; per-row argmin = value-min butterfly +
    // exact-equality first-index + index-min butterfly (bit-identical to the
    // lexicographic reduce: min value is bit-exact one of the d's, and
    // first-occurrence == min index among d==vmin; +/-0 compare equal). ----
    const float4 wkv = *(const float4*)(wkl + c);
#pragma unroll
    for (int r = 0; r < 16; ++r) {
        const float Sr = Srow[r];
        float4 A = acc[r];
        A.x = __fadd_rn(__fsub_rn(Sr, __fmul_rn(2.0f, A.x)), wkv.x);
        A.y = __fadd_rn(__fsub_rn(Sr, __fmul_rn(2.0f, A.y)), wkv.y);
        A.z = __fadd_rn(__fsub_rn(Sr, __fmul_rn(2.0f, A.z)), wkv.z);
        A.w = __fadd_rn(__fsub_rn(Sr, __fmul_rn(2.0f, A.w)), wkv.w);
        acc[r] = A;
        float v = fminf(fminf(A.x, A.y), fminf(A.z, A.w));
#pragma unroll
        for (int m = 1; m < 64; m <<= 1) v = fminf(v, __shfl_xor(v, m, 64));
        int bi = 0x7FFFFFFF;                       // first index with d == vmin
        if (A.w == v) bi = c + 3;
        if (A.z == v) bi = c + 2;
        if (A.y == v) bi = c + 1;
        if (A.x == v) bi = c;
#pragma unroll
        for (int m = 1; m < 64; m <<= 1) bi = min(bi, __shfl_xor(bi, m, 64));
        if (lane == 0) { wminv[r][wave] = v; wmini[r][wave] = bi; }
    }
    __syncthreads();
    if (t < 16) {
        float v = wminv[t][0];
        for (int w = 1; w < 4; ++w) v = fminf(v, wminv[t][w]);
        int bi = 0x7FFFFFFF;
        for (int w = 3; w >= 0; --w)
            if (wminv[t][w] == v) bi = (wmini[t][w] < bi) ? wmini[t][w] : bi;
        rowmin[t] = v;
        out[CODE_OFF + (base + t) * 3 + level] = (float)bi;
    }
    __syncthreads();

    // ---- phase 3: e = exp(dmin - d) in place (fast exp: probs-only path),
    // row sums via shuffle ----
#pragma unroll
    for (int r = 0; r < 16; ++r) {
        const float mn = rowmin[r];
        float4 A = acc[r];
        A.x = __expf(__fsub_rn(mn, A.x));
        A.y = __expf(__fsub_rn(mn, A.y));
        A.z = __expf(__fsub_rn(mn, A.z));
        A.w = __expf(__fsub_rn(mn, A.w));
        acc[r] = A;
        float s = (A.x + A.y) + (A.z + A.w);
#pragma unroll
        for (int m = 1; m < 64; m <<= 1) s += __shfl_xor(s, m, 64);
        if (lane == 0) wsum[r][wave] = s;
    }
    __syncthreads();
    if (t < 16) {
        const float L = (wsum[t][0] + wsum[t][1]) + (wsum[t][2] + wsum[t][3]);
        rcpL[t] = 1.0f / L;
    }
    if (t == 64) {   // commit partial: d at argmin == ||r - q||^2 (loss tolerance loose)
        double cs = 0.0;
        for (int r = 0; r < 16; ++r) cs += (double)rowmin[r];
        atomicAdd(&commit[level], cs);
    }
    __syncthreads();

    // ---- phase 4: avg_probs partials (fp32 atomics, one per code per block) ----
    {
        float s0 = 0.f, s1 = 0.f, s2 = 0.f, s3 = 0.f;
#pragma unroll
        for (int r = 0; r < 16; ++r) {
            const float rl = rcpL[r];
            s0 = fmaf(acc[r].x, rl, s0);
            s1 = fmaf(acc[r].y, rl, s1);
            s2 = fmaf(acc[r].z, rl, s2);
            s3 = fmaf(acc[r].w, rl, s3);
        }
        atomicAdd(&avgp[level * KCODES + c + 0], s0);
        atomicAdd(&avgp[level * KCODES + c + 1], s1);
        atomicAdd(&avgp[level * KCODES + c + 2], s2);
        atomicAdd(&avgp[level * KCODES + c + 3], s3);
    }
}

__global__ __launch_bounds__(256) void finalize_kernel(const float* __restrict__ avgp,
                                                       const double* __restrict__ commit,
                                                       float* __restrict__ out) {
    __shared__ double red[256];
    __shared__ float  kls[3];
    const int t = threadIdx.x;
    for (int l = 0; l < 3; ++l) {
        double p = 0.0;
        for (int k = t; k < KCODES; k += 256) {
            const float avg = avgp[l * KCODES + k] * (1.0f / 131072.0f);
            p += (double)avg * log((double)avg * 1024.0 + 1e-8);
        }
        red[t] = p; __syncthreads();
        for (int off = 128; off >= 1; off >>= 1) {
            if (t < off) red[t] += red[t + off];
            __syncthreads();
        }
        if (t == 0) kls[l] = (float)red[0];
        __syncthreads();
    }
    if (t == 0) {
        float cv = 0.f, u = 0.f;
        for (int l = 0; l < 3; ++l) {
            const float m = (float)(commit[l] * (1.0 / 16777216.0));
            cv = __fadd_rn(cv, m);                      // + mean((sg(r)-q)^2)
            cv = __fadd_rn(cv, __fmul_rn(0.25f, m));    // + BETA * mean((r-sg(q))^2)
            u = __fadd_rn(u, __fmul_rn(1e-3f, kls[l]));
        }
        out[SCAL_OFF]     = cv;
        out[SCAL_OFF + 1] = u;
    }
}

__global__ __launch_bounds__(256) void gather_kernel(const float* __restrict__ W,
                                                     float* __restrict__ out) {
    const size_t g = (size_t)blockIdx.x * 256 + threadIdx.x;   // f4 index
    const size_t n = g >> 5;
    const int f = (int)(g & 31);
    const float* codes = out + CODE_OFF + n * 3;
    const int c0 = (int)codes[0], c1 = (int)codes[1], c2 = (int)codes[2];
    const float4 a = *(const float4*)(W + (size_t)c0 * DIMS + 4 * f);
    const float4 b = *(const float4*)(W + (size_t)(KCODES + c1) * DIMS + 4 * f);
    const float4 c = *(const float4*)(W + (size_t)(2 * KCODES + c2) * DIMS + 4 * f);
    float4 o;   // ((q1 + q2) + q3), fp32 like reference
    o.x = __fadd_rn(__fadd_rn(a.x, b.x), c.x);
    o.y = __fadd_rn(__fadd_rn(a.y, b.y), c.y);
    o.z = __fadd_rn(__fadd_rn(a.z, b.z), c.z);
    o.w = __fadd_rn(__fadd_rn(a.w, b.w), c.w);
    *(float4*)(out + n * DIMS + 4 * f) = o;
}

extern "C" void kernel_launch(void* const* d_in, const int* in_sizes, int n_in,
                              void* d_out, int out_size, void* d_ws, size_t ws_size,
                              hipStream_t stream) {
    const float* x = (const float*)d_in[0];
    const float* W = (const float*)d_in[1];
    float* out = (float*)d_out;
    float*  avgp   = (float*)d_ws;
    double* commit = (double*)((char*)d_ws + WS_COMMIT_OFF);
    float*  wkp    = (float*)((char*)d_ws + WS_WK_OFF);
    float*  WT     = (float*)((char*)d_ws + WS_WT_OFF);

    hipLaunchKernelGGL(init_acc, dim3(1), dim3(256), 0, stream, avgp, commit);
    hipLaunchKernelGGL(wnorm_kernel, dim3(768), dim3(256), 0, stream, W, wkp);
    hipLaunchKernelGGL(transpose_w, dim3(16, 4, 3), dim3(256), 0, stream, W, WT);
    for (int l = 0; l < NLEV; ++l)
        hipLaunchKernelGGL(rvq_level, dim3(NROWS / 16), dim3(256), 0, stream,
                           x, W, WT, wkp, out, avgp, commit, l);
    hipLaunchKernelGGL(finalize_kernel, dim3(1), dim3(256), 0, stream, avgp, commit, out);
    hipLaunchKernelGGL(gather_kernel, dim3((NROWS * 32) / 256), dim3(256), 0, stream, W, out);
}